// Round 7
// baseline (710.526 us; speedup 1.0000x reference)
//
#include <hip/hip_runtime.h>
#include <hip/hip_bf16.h>
#include <hip/hip_fp16.h>

#define TT 24
#define FF 16
#define HH 64
#define GG 192   // 3*HH

typedef __attribute__((ext_vector_type(4))) float f32x4;
typedef __attribute__((ext_vector_type(8))) short s16x8;

__device__ __forceinline__ ushort f2bf(float x){
  union{float f; unsigned u;} c; c.f = x;
  unsigned r = (c.u + 0x7fffu + ((c.u>>16)&1u)) >> 16;
  return (ushort)r;
}
__device__ __forceinline__ float bf2f(ushort h){
  union{unsigned u; float f;} c; c.u = ((unsigned)h)<<16; return c.f;
}
__device__ __forceinline__ float fast_rcp(float x){ return __builtin_amdgcn_rcpf(x); }
__device__ __forceinline__ float sigmoid_f(float x){
  return fast_rcp(1.0f + __expf(-x));
}
__device__ __forceinline__ float tanh_f(float x){
  float e = __expf(-2.0f * fabsf(x));
  float th = (1.0f - e) * fast_rcp(1.0f + e);
  return copysignf(th, x);
}
__device__ __forceinline__ float4 h4tof4(uint2 u){
  __half2 p0 = *(__half2*)&u.x, p1 = *(__half2*)&u.y;
  float2 f0 = __half22float2(p0), f1 = __half22float2(p1);
  return make_float4(f0.x, f0.y, f1.x, f1.y);
}

// ---------------- CSR build ----------------
__global__ void k_zero2(int* __restrict__ a, int* __restrict__ b, int n){
  int i = blockIdx.x*blockDim.x + threadIdx.x;
  if(i<n){ a[i]=0; b[i]=0; }
}

__global__ void k_deg(const int* __restrict__ ei, int E, int* __restrict__ deg){
  int i = blockIdx.x*blockDim.x + threadIdx.x;
  if(i<E) atomicAdd(&deg[ei[E+i]], 1);   // dst = ei[E+i]
}

// exclusive prefix sum of deg -> offsets[0..N]; also dinv = rsqrt(deg+1)
__global__ __launch_bounds__(1024) void k_scan(const int* __restrict__ deg, int* __restrict__ offsets,
                                               float* __restrict__ dinv, int N){
  __shared__ int s[1024];
  int tid = threadIdx.x;
  int CH = (N + 1023) >> 10;
  int lo = tid*CH, hi = min(N, lo+CH);
  int sum=0;
  for(int j=lo;j<hi;j++){
    int d = deg[j];
    dinv[j] = rsqrtf((float)d + 1.0f);
    sum += d;
  }
  s[tid]=sum; __syncthreads();
  for(int o=1;o<1024;o<<=1){
    int v = 0;
    if(tid>=o) v = s[tid-o];
    __syncthreads();
    s[tid] += v;
    __syncthreads();
  }
  int run = s[tid]-sum;
  for(int j=lo;j<hi;j++){ offsets[j]=run; run += deg[j]; }
  if(tid==1023) offsets[N]=s[1023];
}

__global__ void k_fill(const int* __restrict__ ei, int E, const float* __restrict__ dinv,
                       const int* __restrict__ offsets, int* __restrict__ counters,
                       int2* __restrict__ csr2){
  int i = blockIdx.x*blockDim.x + threadIdx.x;
  if(i>=E) return;
  int s = ei[i], d = ei[E+i];
  int slot = offsets[d] + atomicAdd(&counters[d], 1);
  csr2[slot] = make_int2(s, __float_as_int(dinv[s]*dinv[d]));
}

// ---------------- weight prep (merged M1/c1 + w_hh split) ----------------
__global__ void k_prep(const float* __restrict__ gcn_w, const float* __restrict__ gcn_b,
                       const float* __restrict__ w_ih, const float* __restrict__ b_ih,
                       const float* __restrict__ w_hh,
                       ushort* __restrict__ m1H, ushort* __restrict__ m1L, float* __restrict__ c1,
                       ushort* __restrict__ whhH, ushort* __restrict__ whhL){
  int tid = blockIdx.x*blockDim.x + threadIdx.x;
  if(tid < GG*FF){
    int j = tid >> 4, f = tid & 15;
    float s = 0.f;
    for(int k=0;k<HH;k++) s += gcn_w[f*HH+k]*w_ih[j*HH+k];
    ushort h = f2bf(s);
    m1H[tid] = h;
    m1L[tid] = f2bf(s - bf2f(h));
  } else if (tid < GG*FF + GG){
    int j = tid - GG*FF;
    float s = b_ih[j];
    for(int k=0;k<HH;k++) s += gcn_b[k]*w_ih[j*HH+k];
    c1[j] = s;
  }
  if(tid < GG*HH){
    float v = w_hh[tid];
    ushort h = f2bf(v);
    whhH[tid] = h;
    whhL[tid] = f2bf(v - bf2f(h));
  }
}

// ---------------- transpose+convert: x[t][n][f] fp32 -> xTh[n][t*16+f] fp16 ----------------
__global__ __launch_bounds__(256)
void k_xt2(const float* __restrict__ x, ushort* __restrict__ xTh, int N){
  __shared__ ushort tile[16][392];
  const int nbase = blockIdx.x * 16;
  const int tid = threadIdx.x;
  const int nd = tid >> 4, f = tid & 15;
  const int n = nbase + nd;
  for(int t=0; t<TT; t++){
    float v = (n < N) ? x[((size_t)t*N + n)*FF + f] : 0.f;
    tile[nd][t*16 + f] = __half_as_ushort(__float2half(v));
  }
  __syncthreads();
  uint* xo = (uint*)xTh;
  for(int i = tid; i < 16*192; i += 256){
    int d = i / 192, pos = i - d*192;
    int nn = nbase + d;
    if(nn < N) xo[(size_t)nn*192 + pos] = *(uint*)&tile[d][pos*2];
  }
}

// ---------------- aggregation: wave per dst node, fp16 rows, all 24 t at once ----------------
__global__ __launch_bounds__(256)
void k_aggTh(const ushort* __restrict__ xTh, const int* __restrict__ offsets,
             const int2* __restrict__ csr2, const float* __restrict__ dinv,
             ushort* __restrict__ aggH, ushort* __restrict__ aggL, int N){
  int wid = (blockIdx.x*blockDim.x + threadIdx.x) >> 6;
  if(wid >= N) return;
  const int l = threadIdx.x & 63;
  const int half = l >> 5, lh = l & 31;
  const int n = wid;

  float4 a0 = make_float4(0.f,0.f,0.f,0.f);
  float4 a1 = make_float4(0.f,0.f,0.f,0.f);
  float4 a2 = make_float4(0.f,0.f,0.f,0.f);

  const int lo = offsets[n], hi = offsets[n+1];
  for(int j = lo; j < hi; j += 4){
    int ja = j + half;
    int jb = j + 2 + half;
    bool okA = ja < hi, okB = jb < hi;
    int2 cA = csr2[okA ? ja : lo];
    int2 cB = csr2[okB ? jb : lo];
    float wA = okA ? __int_as_float(cA.y) : 0.f;
    float wB = okB ? __int_as_float(cB.y) : 0.f;
    const uint2* rA = (const uint2*)(xTh + (size_t)cA.x*384) + lh;
    const uint2* rB = (const uint2*)(xTh + (size_t)cB.x*384) + lh;
    uint2 uA0 = rA[0], uA1 = rA[32], uA2 = rA[64];
    uint2 uB0 = rB[0], uB1 = rB[32], uB2 = rB[64];
    float4 vA0 = h4tof4(uA0), vA1 = h4tof4(uA1), vA2 = h4tof4(uA2);
    float4 vB0 = h4tof4(uB0), vB1 = h4tof4(uB1), vB2 = h4tof4(uB2);
    a0.x += wA*vA0.x; a0.y += wA*vA0.y; a0.z += wA*vA0.z; a0.w += wA*vA0.w;
    a1.x += wA*vA1.x; a1.y += wA*vA1.y; a1.z += wA*vA1.z; a1.w += wA*vA1.w;
    a2.x += wA*vA2.x; a2.y += wA*vA2.y; a2.z += wA*vA2.z; a2.w += wA*vA2.w;
    a0.x += wB*vB0.x; a0.y += wB*vB0.y; a0.z += wB*vB0.z; a0.w += wB*vB0.w;
    a1.x += wB*vB1.x; a1.y += wB*vB1.y; a1.z += wB*vB1.z; a1.w += wB*vB1.w;
    a2.x += wB*vB2.x; a2.y += wB*vB2.y; a2.z += wB*vB2.z; a2.w += wB*vB2.w;
  }
  a0.x += __shfl_xor(a0.x, 32, 64); a0.y += __shfl_xor(a0.y, 32, 64);
  a0.z += __shfl_xor(a0.z, 32, 64); a0.w += __shfl_xor(a0.w, 32, 64);
  a1.x += __shfl_xor(a1.x, 32, 64); a1.y += __shfl_xor(a1.y, 32, 64);
  a1.z += __shfl_xor(a1.z, 32, 64); a1.w += __shfl_xor(a1.w, 32, 64);
  a2.x += __shfl_xor(a2.x, 32, 64); a2.y += __shfl_xor(a2.y, 32, 64);
  a2.z += __shfl_xor(a2.z, 32, 64); a2.w += __shfl_xor(a2.w, 32, 64);

  if(half == 0){
    float sn = dinv[n]; sn *= sn;
    const uint2* rS = (const uint2*)(xTh + (size_t)n*384) + lh;
    float4 s0 = h4tof4(rS[0]), s1 = h4tof4(rS[32]), s2 = h4tof4(rS[64]);
    a0.x += sn*s0.x; a0.y += sn*s0.y; a0.z += sn*s0.z; a0.w += sn*s0.w;
    a1.x += sn*s1.x; a1.y += sn*s1.y; a1.z += sn*s1.z; a1.w += sn*s1.w;
    a2.x += sn*s2.x; a2.y += sn*s2.y; a2.z += sn*s2.z; a2.w += sn*s2.w;
    float4 acc[3] = {a0, a1, a2};
    #pragma unroll
    for(int k=0;k<3;k++){
      int u  = lh + k*32;
      int t  = u >> 2, f4 = u & 3;
      size_t o = ((size_t)t*N + n)*FF + f4*4;
      float4 a = acc[k];
      ushort4 h, lw;
      h.x = f2bf(a.x); lw.x = f2bf(a.x - bf2f(h.x));
      h.y = f2bf(a.y); lw.y = f2bf(a.y - bf2f(h.y));
      h.z = f2bf(a.z); lw.z = f2bf(a.z - bf2f(h.z));
      h.w = f2bf(a.w); lw.w = f2bf(a.w - bf2f(h.w));
      *(ushort4*)(aggH + o) = h;
      *(ushort4*)(aggL + o) = lw;
    }
  }
}

// ---------------- persistent MFMA GRU, 32 nodes/block, prefetched agg ----------------
// block = 256 = 4 waves; wave w owns channels [w*16,w*16+16) for the block's 32 nodes.
__global__ __launch_bounds__(256, 3)
void k_gru_all(const ushort* __restrict__ aggH, const ushort* __restrict__ aggL,
               const ushort* __restrict__ whhH, const ushort* __restrict__ whhL,
               const ushort* __restrict__ m1H,  const ushort* __restrict__ m1L,
               const float* __restrict__ c1, const float* __restrict__ bhh,
               const float* __restrict__ lin_w, const float* __restrict__ lin_b,
               float* __restrict__ out, int N, int P){
  __shared__ __align__(16) ushort hb[2][2][32*64];   // [buf][hi/lo][node*64+ch] swizzled, 16 KB
  const int tid  = threadIdx.x;
  const int l    = tid & 63, w = tid >> 6;
  const int lrow = l & 15;
  const int lgrp = l >> 4;
  const int ch   = w*16 + lrow;
  const int nbase = blockIdx.x * 32;

  // weight fragments (stationary)
  s16x8 bH[3][2], bL[3][2], mHf[3], mLf[3];
  #pragma unroll
  for(int g=0; g<3; g++){
    int j = g*HH + w*16 + lrow;
    #pragma unroll
    for(int ks=0; ks<2; ks++){
      int k0 = ks*32 + lgrp*8;
      bH[g][ks] = *(const s16x8*)(whhH + j*HH + k0);
      bL[g][ks] = *(const s16x8*)(whhL + j*HH + k0);
    }
    if(lgrp < 2){
      int k0 = lgrp*8;
      mHf[g] = *(const s16x8*)(m1H + j*FF + k0);
      mLf[g] = *(const s16x8*)(m1L + j*FF + k0);
    } else {
      mHf[g] = (s16x8){0,0,0,0,0,0,0,0};
      mLf[g] = (s16x8){0,0,0,0,0,0,0,0};
    }
  }

  const float cbr = c1[ch]      + bhh[ch];
  const float cbz = c1[ch+HH]   + bhh[ch+HH];
  const float c1n = c1[ch+2*HH];
  const float bhn = bhh[ch+2*HH];

  float hreg[8];
  #pragma unroll
  for(int i=0;i<8;i++) hreg[i]=0.f;

  // agg fragment addresses (A rows = nodes nt*16+lrow; K slice lgrp*8..+7, lgrp<2 active)
  const bool agAct = (lgrp < 2);
  const size_t ao0 = (size_t)min(nbase      + lrow, N-1)*FF + (lgrp&1)*8;
  const size_t ao1 = (size_t)min(nbase + 16 + lrow, N-1)*FF + (lgrp&1)*8;
  const s16x8 zf = (s16x8){0,0,0,0,0,0,0,0};

  // prefetch t=0
  s16x8 cH0, cL0, cH1, cL1;
  {
    const ushort* aHt = aggH;  const ushort* aLt = aggL;
    cH0 = agAct ? *(const s16x8*)(aHt + ao0) : zf;
    cL0 = agAct ? *(const s16x8*)(aLt + ao0) : zf;
    cH1 = agAct ? *(const s16x8*)(aHt + ao1) : zf;
    cL1 = agAct ? *(const s16x8*)(aLt + ao1) : zf;
  }

  // zero h buffer 0: 2 planes x 2048 ushorts = 2048 dwords
  {
    uint* p = (uint*)&hb[0][0][0];
    for(int i=tid; i<2048; i+=256) p[i]=0u;
  }
  __syncthreads();

  for(int t=0; t<TT; t++){
    const int cur = t & 1, nxt = cur ^ 1;

    // LDS reads of h for both nt
    s16x8 ahH[2][2], ahL[2][2];
    #pragma unroll
    for(int nt=0; nt<2; nt++){
      const int r = nt*16 + lrow;
      #pragma unroll
      for(int ks=0; ks<2; ks++){
        int idx = (r*64 + ks*32 + lgrp*8) ^ ((r&7)<<3);
        ahH[nt][ks] = *(const s16x8*)&hb[cur][0][idx];
        ahL[nt][ks] = *(const s16x8*)&hb[cur][1][idx];
      }
    }

    // prefetch agg for t+1 (hides HBM latency under MFMA+epilogue+barrier)
    s16x8 pH0=zf, pL0=zf, pH1=zf, pL1=zf;
    if(t+1 < TT && agAct){
      const ushort* aHt = aggH + (size_t)(t+1)*N*FF;
      const ushort* aLt = aggL + (size_t)(t+1)*N*FF;
      pH0 = *(const s16x8*)(aHt + ao0);
      pL0 = *(const s16x8*)(aLt + ao0);
      pH1 = *(const s16x8*)(aHt + ao1);
      pL1 = *(const s16x8*)(aLt + ao1);
    }

    #pragma unroll
    for(int nt=0; nt<2; nt++){
      const s16x8 agHf = nt ? cH1 : cH0;
      const s16x8 agLf = nt ? cL1 : cL0;

      f32x4 aR = {0.f,0.f,0.f,0.f}, aZ = {0.f,0.f,0.f,0.f};
      f32x4 aNi= {0.f,0.f,0.f,0.f}, aNh= {0.f,0.f,0.f,0.f};
      #pragma unroll
      for(int ks=0; ks<2; ks++){
        aR = __builtin_amdgcn_mfma_f32_16x16x32_bf16(ahH[nt][ks], bH[0][ks], aR, 0,0,0);
        aR = __builtin_amdgcn_mfma_f32_16x16x32_bf16(ahL[nt][ks], bH[0][ks], aR, 0,0,0);
        aR = __builtin_amdgcn_mfma_f32_16x16x32_bf16(ahH[nt][ks], bL[0][ks], aR, 0,0,0);
        aZ = __builtin_amdgcn_mfma_f32_16x16x32_bf16(ahH[nt][ks], bH[1][ks], aZ, 0,0,0);
        aZ = __builtin_amdgcn_mfma_f32_16x16x32_bf16(ahL[nt][ks], bH[1][ks], aZ, 0,0,0);
        aZ = __builtin_amdgcn_mfma_f32_16x16x32_bf16(ahH[nt][ks], bL[1][ks], aZ, 0,0,0);
        aNh= __builtin_amdgcn_mfma_f32_16x16x32_bf16(ahH[nt][ks], bH[2][ks], aNh,0,0,0);
        aNh= __builtin_amdgcn_mfma_f32_16x16x32_bf16(ahL[nt][ks], bH[2][ks], aNh,0,0,0);
        aNh= __builtin_amdgcn_mfma_f32_16x16x32_bf16(ahH[nt][ks], bL[2][ks], aNh,0,0,0);
      }
      aR  = __builtin_amdgcn_mfma_f32_16x16x32_bf16(agHf, mHf[0], aR, 0,0,0);
      aR  = __builtin_amdgcn_mfma_f32_16x16x32_bf16(agLf, mHf[0], aR, 0,0,0);
      aR  = __builtin_amdgcn_mfma_f32_16x16x32_bf16(agHf, mLf[0], aR, 0,0,0);
      aZ  = __builtin_amdgcn_mfma_f32_16x16x32_bf16(agHf, mHf[1], aZ, 0,0,0);
      aZ  = __builtin_amdgcn_mfma_f32_16x16x32_bf16(agLf, mHf[1], aZ, 0,0,0);
      aZ  = __builtin_amdgcn_mfma_f32_16x16x32_bf16(agHf, mLf[1], aZ, 0,0,0);
      aNi = __builtin_amdgcn_mfma_f32_16x16x32_bf16(agHf, mHf[2], aNi,0,0,0);
      aNi = __builtin_amdgcn_mfma_f32_16x16x32_bf16(agLf, mHf[2], aNi,0,0,0);
      aNi = __builtin_amdgcn_mfma_f32_16x16x32_bf16(agHf, mLf[2], aNi,0,0,0);

      #pragma unroll
      for(int i=0;i<4;i++){
        float r_ = sigmoid_f(aR[i] + cbr);
        float z_ = sigmoid_f(aZ[i] + cbz);
        float nn = tanh_f(aNi[i] + c1n + r_*(aNh[i] + bhn));
        int hidx = nt*4 + i;
        float hp = hreg[hidx];
        float hn = nn + z_*(hp - nn);
        hreg[hidx] = hn;
        int noderow = nt*16 + lgrp*4 + i;
        int idx = (noderow*64 + ch) ^ ((noderow&7)<<3);
        ushort hiw = f2bf(hn);
        hb[nxt][0][idx] = hiw;
        hb[nxt][1][idx] = f2bf(hn - bf2f(hiw));
      }
    }
    __syncthreads();

    cH0 = pH0; cL0 = pL0; cH1 = pH1; cL1 = pL1;
  }

  // ---- fused linear head ----
  float* hs = (float*)&hb[0][0][0];
  #pragma unroll
  for(int hidx=0; hidx<8; hidx++){
    int nt = hidx >> 2, i = hidx & 3;
    int r = nt*16 + lgrp*4 + i;
    hs[r*64 + ch] = hreg[hidx];
  }
  __syncthreads();
  {
    int r = l;
    int node = nbase + r;
    if(r < 32 && node < N){
      float hv[HH];
      #pragma unroll
      for(int q=0;q<16;q++){
        float4 v = *(const float4*)&hs[r*64 + q*4];
        hv[4*q]=v.x; hv[4*q+1]=v.y; hv[4*q+2]=v.z; hv[4*q+3]=v.w;
      }
      for(int p=w; p<P; p+=4){
        float acc = lin_b[p];
        #pragma unroll
        for(int k=0;k<HH;k++) acc += hv[k]*lin_w[p*HH+k];
        out[(size_t)p*N + node] = acc;
      }
    }
  }
}

extern "C" void kernel_launch(void* const* d_in, const int* in_sizes, int n_in,
                              void* d_out, int out_size, void* d_ws, size_t ws_size,
                              hipStream_t stream){
  const float* x     = (const float*)d_in[0];
  const float* gcn_w = (const float*)d_in[2];
  const float* gcn_b = (const float*)d_in[3];
  const float* w_ih  = (const float*)d_in[4];
  const float* w_hh  = (const float*)d_in[5];
  const float* b_ih  = (const float*)d_in[6];
  const float* b_hh  = (const float*)d_in[7];
  const float* lin_w = (const float*)d_in[8];
  const float* lin_b = (const float*)d_in[9];
  const int*   ei    = (const int*)d_in[10];
  const int E = in_sizes[10]/2;
  const int N = in_sizes[0]/(TT*FF);
  const int P = in_sizes[9];

  char* wsp = (char*)d_ws;
  auto alloc = [&](size_t bytes)->void*{ void* p = wsp; wsp += (bytes + 255) & ~(size_t)255; return p; };
  int*    deg      = (int*)   alloc((size_t)N*4);
  int*    counters = (int*)   alloc((size_t)N*4);
  int*    offsets  = (int*)   alloc((size_t)(N+1)*4);
  float*  dinv     = (float*) alloc((size_t)N*4);
  int2*   csr2     = (int2*)  alloc((size_t)E*8);
  ushort* xTh      = (ushort*)alloc((size_t)N*384*2);
  ushort* aggH     = (ushort*)alloc((size_t)TT*N*FF*2);
  ushort* aggL     = (ushort*)alloc((size_t)TT*N*FF*2);
  ushort* m1H      = (ushort*)alloc((size_t)GG*FF*2);
  ushort* m1L      = (ushort*)alloc((size_t)GG*FF*2);
  float*  c1       = (float*) alloc((size_t)GG*4);
  ushort* whhH     = (ushort*)alloc((size_t)GG*HH*2);
  ushort* whhL     = (ushort*)alloc((size_t)GG*HH*2);

  k_zero2<<<(N+255)/256, 256, 0, stream>>>(deg, counters, N);
  k_deg  <<<(E+255)/256, 256, 0, stream>>>(ei, E, deg);
  k_scan <<<1, 1024, 0, stream>>>(deg, offsets, dinv, N);
  k_fill <<<(E+255)/256, 256, 0, stream>>>(ei, E, dinv, offsets, counters, csr2);
  k_prep <<<(GG*HH+255)/256, 256, 0, stream>>>(gcn_w, gcn_b, w_ih, b_ih, w_hh,
                                               m1H, m1L, c1, whhH, whhL);
  k_xt2  <<<(N+15)/16, 256, 0, stream>>>(x, xTh, N);
  k_aggTh<<<(N+3)/4, 256, 0, stream>>>(xTh, offsets, csr2, dinv, aggH, aggL, N);
  k_gru_all<<<(N+31)/32, 256, 0, stream>>>(aggH, aggL, whhH, whhL, m1H, m1L, c1, b_hh,
                                           lin_w, lin_b, (float*)d_out, N, P);
}

// Round 8
// 619.641 us; speedup vs baseline: 1.1467x; 1.1467x over previous
//
#include <hip/hip_runtime.h>
#include <hip/hip_bf16.h>
#include <hip/hip_fp16.h>

#define TT 24
#define FF 16
#define HH 64
#define GG 192   // 3*HH

typedef __attribute__((ext_vector_type(4))) float f32x4;
typedef __attribute__((ext_vector_type(8))) short s16x8;

__device__ __forceinline__ ushort f2bf(float x){
  union{float f; unsigned u;} c; c.f = x;
  unsigned r = (c.u + 0x7fffu + ((c.u>>16)&1u)) >> 16;
  return (ushort)r;
}
__device__ __forceinline__ float bf2f(ushort h){
  union{unsigned u; float f;} c; c.u = ((unsigned)h)<<16; return c.f;
}
__device__ __forceinline__ float fast_rcp(float x){ return __builtin_amdgcn_rcpf(x); }
__device__ __forceinline__ float sigmoid_f(float x){
  return fast_rcp(1.0f + __expf(-x));
}
__device__ __forceinline__ float tanh_f(float x){
  float e = __expf(-2.0f * fabsf(x));
  float th = (1.0f - e) * fast_rcp(1.0f + e);
  return copysignf(th, x);
}
__device__ __forceinline__ float4 h4tof4(uint2 u){
  __half2 p0 = *(__half2*)&u.x, p1 = *(__half2*)&u.y;
  float2 f0 = __half22float2(p0), f1 = __half22float2(p1);
  return make_float4(f0.x, f0.y, f1.x, f1.y);
}

// ---------------- CSR build ----------------
__global__ void k_zero2(int* __restrict__ a, int* __restrict__ b, int n){
  int i = blockIdx.x*blockDim.x + threadIdx.x;
  if(i<n){ a[i]=0; b[i]=0; }
}

__global__ void k_deg(const int* __restrict__ ei, int E, int* __restrict__ deg){
  int i = blockIdx.x*blockDim.x + threadIdx.x;
  if(i<E) atomicAdd(&deg[ei[E+i]], 1);   // dst = ei[E+i]
}

__global__ __launch_bounds__(1024) void k_scan(const int* __restrict__ deg, int* __restrict__ offsets,
                                               float* __restrict__ dinv, int N){
  __shared__ int s[1024];
  int tid = threadIdx.x;
  int CH = (N + 1023) >> 10;
  int lo = tid*CH, hi = min(N, lo+CH);
  int sum=0;
  for(int j=lo;j<hi;j++){
    int d = deg[j];
    dinv[j] = rsqrtf((float)d + 1.0f);
    sum += d;
  }
  s[tid]=sum; __syncthreads();
  for(int o=1;o<1024;o<<=1){
    int v = 0;
    if(tid>=o) v = s[tid-o];
    __syncthreads();
    s[tid] += v;
    __syncthreads();
  }
  int run = s[tid]-sum;
  for(int j=lo;j<hi;j++){ offsets[j]=run; run += deg[j]; }
  if(tid==1023) offsets[N]=s[1023];
}

__global__ void k_fill(const int* __restrict__ ei, int E, const float* __restrict__ dinv,
                       const int* __restrict__ offsets, int* __restrict__ counters,
                       int2* __restrict__ csr2){
  int i = blockIdx.x*blockDim.x + threadIdx.x;
  if(i>=E) return;
  int s = ei[i], d = ei[E+i];
  int slot = offsets[d] + atomicAdd(&counters[d], 1);
  csr2[slot] = make_int2(s, __float_as_int(dinv[s]*dinv[d]));
}

// ---------------- weight prep ----------------
__global__ void k_prep(const float* __restrict__ gcn_w, const float* __restrict__ gcn_b,
                       const float* __restrict__ w_ih, const float* __restrict__ b_ih,
                       const float* __restrict__ w_hh,
                       ushort* __restrict__ m1H, ushort* __restrict__ m1L, float* __restrict__ c1,
                       ushort* __restrict__ whhH, ushort* __restrict__ whhL){
  int tid = blockIdx.x*blockDim.x + threadIdx.x;
  if(tid < GG*FF){
    int j = tid >> 4, f = tid & 15;
    float s = 0.f;
    for(int k=0;k<HH;k++) s += gcn_w[f*HH+k]*w_ih[j*HH+k];
    ushort h = f2bf(s);
    m1H[tid] = h;
    m1L[tid] = f2bf(s - bf2f(h));
  } else if (tid < GG*FF + GG){
    int j = tid - GG*FF;
    float s = b_ih[j];
    for(int k=0;k<HH;k++) s += gcn_b[k]*w_ih[j*HH+k];
    c1[j] = s;
  }
  if(tid < GG*HH){
    float v = w_hh[tid];
    ushort h = f2bf(v);
    whhH[tid] = h;
    whhL[tid] = f2bf(v - bf2f(h));
  }
}

// ---------------- transpose+convert: x[t][n][f] fp32 -> xTh[n][t*16+f] fp16 ----------------
__global__ __launch_bounds__(256)
void k_xt2(const float* __restrict__ x, ushort* __restrict__ xTh, int N){
  __shared__ ushort tile[16][392];
  const int nbase = blockIdx.x * 16;
  const int tid = threadIdx.x;
  const int nd = tid >> 4, f = tid & 15;
  const int n = nbase + nd;
  for(int t=0; t<TT; t++){
    float v = (n < N) ? x[((size_t)t*N + n)*FF + f] : 0.f;
    tile[nd][t*16 + f] = __half_as_ushort(__float2half(v));
  }
  __syncthreads();
  uint* xo = (uint*)xTh;
  for(int i = tid; i < 16*192; i += 256){
    int d = i / 192, pos = i - d*192;
    int nn = nbase + d;
    if(nn < N) xo[(size_t)nn*192 + pos] = *(uint*)&tile[d][pos*2];
  }
}

// ---------------- aggregation: wave per dst node, fp16 rows, all 24 t at once ----------------
__global__ __launch_bounds__(256)
void k_aggTh(const ushort* __restrict__ xTh, const int* __restrict__ offsets,
             const int2* __restrict__ csr2, const float* __restrict__ dinv,
             ushort* __restrict__ aggH, ushort* __restrict__ aggL, int N){
  int wid = (blockIdx.x*blockDim.x + threadIdx.x) >> 6;
  if(wid >= N) return;
  const int l = threadIdx.x & 63;
  const int half = l >> 5, lh = l & 31;
  const int n = wid;

  float4 a0 = make_float4(0.f,0.f,0.f,0.f);
  float4 a1 = make_float4(0.f,0.f,0.f,0.f);
  float4 a2 = make_float4(0.f,0.f,0.f,0.f);

  const int lo = offsets[n], hi = offsets[n+1];
  for(int j = lo; j < hi; j += 4){
    int ja = j + half;
    int jb = j + 2 + half;
    bool okA = ja < hi, okB = jb < hi;
    int2 cA = csr2[okA ? ja : lo];
    int2 cB = csr2[okB ? jb : lo];
    float wA = okA ? __int_as_float(cA.y) : 0.f;
    float wB = okB ? __int_as_float(cB.y) : 0.f;
    const uint2* rA = (const uint2*)(xTh + (size_t)cA.x*384) + lh;
    const uint2* rB = (const uint2*)(xTh + (size_t)cB.x*384) + lh;
    uint2 uA0 = rA[0], uA1 = rA[32], uA2 = rA[64];
    uint2 uB0 = rB[0], uB1 = rB[32], uB2 = rB[64];
    float4 vA0 = h4tof4(uA0), vA1 = h4tof4(uA1), vA2 = h4tof4(uA2);
    float4 vB0 = h4tof4(uB0), vB1 = h4tof4(uB1), vB2 = h4tof4(uB2);
    a0.x += wA*vA0.x; a0.y += wA*vA0.y; a0.z += wA*vA0.z; a0.w += wA*vA0.w;
    a1.x += wA*vA1.x; a1.y += wA*vA1.y; a1.z += wA*vA1.z; a1.w += wA*vA1.w;
    a2.x += wA*vA2.x; a2.y += wA*vA2.y; a2.z += wA*vA2.z; a2.w += wA*vA2.w;
    a0.x += wB*vB0.x; a0.y += wB*vB0.y; a0.z += wB*vB0.z; a0.w += wB*vB0.w;
    a1.x += wB*vB1.x; a1.y += wB*vB1.y; a1.z += wB*vB1.z; a1.w += wB*vB1.w;
    a2.x += wB*vB2.x; a2.y += wB*vB2.y; a2.z += wB*vB2.z; a2.w += wB*vB2.w;
  }
  a0.x += __shfl_xor(a0.x, 32, 64); a0.y += __shfl_xor(a0.y, 32, 64);
  a0.z += __shfl_xor(a0.z, 32, 64); a0.w += __shfl_xor(a0.w, 32, 64);
  a1.x += __shfl_xor(a1.x, 32, 64); a1.y += __shfl_xor(a1.y, 32, 64);
  a1.z += __shfl_xor(a1.z, 32, 64); a1.w += __shfl_xor(a1.w, 32, 64);
  a2.x += __shfl_xor(a2.x, 32, 64); a2.y += __shfl_xor(a2.y, 32, 64);
  a2.z += __shfl_xor(a2.z, 32, 64); a2.w += __shfl_xor(a2.w, 32, 64);

  if(half == 0){
    float sn = dinv[n]; sn *= sn;
    const uint2* rS = (const uint2*)(xTh + (size_t)n*384) + lh;
    float4 s0 = h4tof4(rS[0]), s1 = h4tof4(rS[32]), s2 = h4tof4(rS[64]);
    a0.x += sn*s0.x; a0.y += sn*s0.y; a0.z += sn*s0.z; a0.w += sn*s0.w;
    a1.x += sn*s1.x; a1.y += sn*s1.y; a1.z += sn*s1.z; a1.w += sn*s1.w;
    a2.x += sn*s2.x; a2.y += sn*s2.y; a2.z += sn*s2.z; a2.w += sn*s2.w;
    float4 acc[3] = {a0, a1, a2};
    #pragma unroll
    for(int k=0;k<3;k++){
      int u  = lh + k*32;
      int t  = u >> 2, f4 = u & 3;
      size_t o = ((size_t)t*N + n)*FF + f4*4;
      float4 a = acc[k];
      ushort4 h, lw;
      h.x = f2bf(a.x); lw.x = f2bf(a.x - bf2f(h.x));
      h.y = f2bf(a.y); lw.y = f2bf(a.y - bf2f(h.y));
      h.z = f2bf(a.z); lw.z = f2bf(a.z - bf2f(h.z));
      h.w = f2bf(a.w); lw.w = f2bf(a.w - bf2f(h.w));
      *(ushort4*)(aggH + o) = h;
      *(ushort4*)(aggL + o) = lw;
    }
  }
}

// ---------------- persistent MFMA GRU, 32 nodes/block, stacked 2-term MFMA ----------------
// block = 256 = 4 waves; wave w owns channels [w*16,w*16+16) for the block's 32 nodes.
// hidden: (hH+hL)*WH via K-stacking (4 MFMA/gate reusing bH); input: (aggH+aggL)*m1H
// via lgrp-plane stacking (1 MFMA/gate, all 64 lanes active).
__global__ __launch_bounds__(256, 4)
void k_gru_all(const ushort* __restrict__ aggH, const ushort* __restrict__ aggL,
               const ushort* __restrict__ whhH, const ushort* __restrict__ whhL,
               const ushort* __restrict__ m1H,
               const float* __restrict__ c1, const float* __restrict__ bhh,
               const float* __restrict__ lin_w, const float* __restrict__ lin_b,
               float* __restrict__ out, int N, int P){
  __shared__ __align__(16) ushort hb[2][2][32*64];   // [buf][hi/lo][node*64+ch] swizzled, 16 KB
  const int tid  = threadIdx.x;
  const int l    = tid & 63, w = tid >> 6;
  const int lrow = l & 15;
  const int lgrp = l >> 4;
  const int ch   = w*16 + lrow;
  const int nbase = blockIdx.x * 32;

  // stationary weights: hidden hi only (stacked), input m1H duplicated across lgrp pairs
  s16x8 bH[3][2], mS[3];
  #pragma unroll
  for(int g=0; g<3; g++){
    int j = g*HH + w*16 + lrow;
    #pragma unroll
    for(int ks=0; ks<2; ks++)
      bH[g][ks] = *(const s16x8*)(whhH + j*HH + ks*32 + lgrp*8);
    mS[g] = *(const s16x8*)(m1H + j*FF + (lgrp&1)*8);
  }

  const float cbr = c1[ch]      + bhh[ch];
  const float cbz = c1[ch+HH]   + bhh[ch+HH];
  const float c1n = c1[ch+2*HH];
  const float bhn = bhh[ch+2*HH];

  float hreg[8];
  #pragma unroll
  for(int i=0;i<8;i++) hreg[i]=0.f;

  // stacked input A-frag source: lgrp<2 -> aggH plane (k 0..15), lgrp>=2 -> aggL (k 16..31)
  const ushort* agPlane = (lgrp < 2) ? aggH : aggL;
  const size_t ao0 = (size_t)min(nbase      + lrow, N-1)*FF + (lgrp&1)*8;
  const size_t ao1 = (size_t)min(nbase + 16 + lrow, N-1)*FF + (lgrp&1)*8;

  // prefetch t=0
  s16x8 cS0 = *(const s16x8*)(agPlane + ao0);
  s16x8 cS1 = *(const s16x8*)(agPlane + ao1);

  {
    uint* p = (uint*)&hb[0][0][0];
    for(int i=tid; i<2048; i+=256) p[i]=0u;
  }
  __syncthreads();

  for(int t=0; t<TT; t++){
    const int cur = t & 1, nxt = cur ^ 1;

    // prefetch agg for t+1 (hides HBM latency under MFMA+epilogue+barrier)
    s16x8 pS0 = cS0, pS1 = cS1;
    if(t+1 < TT){
      const ushort* ap = agPlane + (size_t)(t+1)*N*FF;
      pS0 = *(const s16x8*)(ap + ao0);
      pS1 = *(const s16x8*)(ap + ao1);
    }

    #pragma unroll
    for(int nt=0; nt<2; nt++){
      // LDS reads of h (hi and lo planes)
      s16x8 ahH[2], ahL[2];
      const int r = nt*16 + lrow;
      #pragma unroll
      for(int ks=0; ks<2; ks++){
        int idx = (r*64 + ks*32 + lgrp*8) ^ ((r&7)<<3);
        ahH[ks] = *(const s16x8*)&hb[cur][0][idx];
        ahL[ks] = *(const s16x8*)&hb[cur][1][idx];
      }
      const s16x8 agS = nt ? cS1 : cS0;

      f32x4 aR = {0.f,0.f,0.f,0.f}, aZ = {0.f,0.f,0.f,0.f};
      f32x4 aNi= {0.f,0.f,0.f,0.f}, aNh= {0.f,0.f,0.f,0.f};
      // hidden: (hH+hL)·WH  (K=128 stacked, bH reused)
      aR = __builtin_amdgcn_mfma_f32_16x16x32_bf16(ahH[0], bH[0][0], aR, 0,0,0);
      aR = __builtin_amdgcn_mfma_f32_16x16x32_bf16(ahH[1], bH[0][1], aR, 0,0,0);
      aR = __builtin_amdgcn_mfma_f32_16x16x32_bf16(ahL[0], bH[0][0], aR, 0,0,0);
      aR = __builtin_amdgcn_mfma_f32_16x16x32_bf16(ahL[1], bH[0][1], aR, 0,0,0);
      aZ = __builtin_amdgcn_mfma_f32_16x16x32_bf16(ahH[0], bH[1][0], aZ, 0,0,0);
      aZ = __builtin_amdgcn_mfma_f32_16x16x32_bf16(ahH[1], bH[1][1], aZ, 0,0,0);
      aZ = __builtin_amdgcn_mfma_f32_16x16x32_bf16(ahL[0], bH[1][0], aZ, 0,0,0);
      aZ = __builtin_amdgcn_mfma_f32_16x16x32_bf16(ahL[1], bH[1][1], aZ, 0,0,0);
      aNh= __builtin_amdgcn_mfma_f32_16x16x32_bf16(ahH[0], bH[2][0], aNh,0,0,0);
      aNh= __builtin_amdgcn_mfma_f32_16x16x32_bf16(ahH[1], bH[2][1], aNh,0,0,0);
      aNh= __builtin_amdgcn_mfma_f32_16x16x32_bf16(ahL[0], bH[2][0], aNh,0,0,0);
      aNh= __builtin_amdgcn_mfma_f32_16x16x32_bf16(ahL[1], bH[2][1], aNh,0,0,0);
      // input: (aggH+aggL)·m1H  (lgrp-plane stacked, 1 MFMA per gate)
      aR  = __builtin_amdgcn_mfma_f32_16x16x32_bf16(agS, mS[0], aR, 0,0,0);
      aZ  = __builtin_amdgcn_mfma_f32_16x16x32_bf16(agS, mS[1], aZ, 0,0,0);
      aNi = __builtin_amdgcn_mfma_f32_16x16x32_bf16(agS, mS[2], aNi,0,0,0);

      #pragma unroll
      for(int i=0;i<4;i++){
        float r_ = sigmoid_f(aR[i] + cbr);
        float z_ = sigmoid_f(aZ[i] + cbz);
        float nn = tanh_f(aNi[i] + c1n + r_*(aNh[i] + bhn));
        int hidx = nt*4 + i;
        float hp = hreg[hidx];
        float hn = nn + z_*(hp - nn);
        hreg[hidx] = hn;
        int noderow = nt*16 + lgrp*4 + i;
        int idx = (noderow*64 + ch) ^ ((noderow&7)<<3);
        ushort hiw = f2bf(hn);
        hb[nxt][0][idx] = hiw;
        hb[nxt][1][idx] = f2bf(hn - bf2f(hiw));
      }
    }
    __syncthreads();

    cS0 = pS0; cS1 = pS1;
  }

  // ---- fused linear head ----
  float* hs = (float*)&hb[0][0][0];
  #pragma unroll
  for(int hidx=0; hidx<8; hidx++){
    int nt = hidx >> 2, i = hidx & 3;
    int r = nt*16 + lgrp*4 + i;
    hs[r*64 + ch] = hreg[hidx];
  }
  __syncthreads();
  {
    int r = l;
    int node = nbase + r;
    if(r < 32 && node < N){
      float hv[HH];
      #pragma unroll
      for(int q=0;q<16;q++){
        float4 v = *(const float4*)&hs[r*64 + q*4];
        hv[4*q]=v.x; hv[4*q+1]=v.y; hv[4*q+2]=v.z; hv[4*q+3]=v.w;
      }
      for(int p=w; p<P; p+=4){
        float acc = lin_b[p];
        #pragma unroll
        for(int k=0;k<HH;k++) acc += hv[k]*lin_w[p*HH+k];
        out[(size_t)p*N + node] = acc;
      }
    }
  }
}

extern "C" void kernel_launch(void* const* d_in, const int* in_sizes, int n_in,
                              void* d_out, int out_size, void* d_ws, size_t ws_size,
                              hipStream_t stream){
  const float* x     = (const float*)d_in[0];
  const float* gcn_w = (const float*)d_in[2];
  const float* gcn_b = (const float*)d_in[3];
  const float* w_ih  = (const float*)d_in[4];
  const float* w_hh  = (const float*)d_in[5];
  const float* b_ih  = (const float*)d_in[6];
  const float* b_hh  = (const float*)d_in[7];
  const float* lin_w = (const float*)d_in[8];
  const float* lin_b = (const float*)d_in[9];
  const int*   ei    = (const int*)d_in[10];
  const int E = in_sizes[10]/2;
  const int N = in_sizes[0]/(TT*FF);
  const int P = in_sizes[9];

  char* wsp = (char*)d_ws;
  auto alloc = [&](size_t bytes)->void*{ void* p = wsp; wsp += (bytes + 255) & ~(size_t)255; return p; };
  int*    deg      = (int*)   alloc((size_t)N*4);
  int*    counters = (int*)   alloc((size_t)N*4);
  int*    offsets  = (int*)   alloc((size_t)(N+1)*4);
  float*  dinv     = (float*) alloc((size_t)N*4);
  int2*   csr2     = (int2*)  alloc((size_t)E*8);
  ushort* xTh      = (ushort*)alloc((size_t)N*384*2);
  ushort* aggH     = (ushort*)alloc((size_t)TT*N*FF*2);
  ushort* aggL     = (ushort*)alloc((size_t)TT*N*FF*2);
  ushort* m1H      = (ushort*)alloc((size_t)GG*FF*2);
  ushort* m1L      = (ushort*)alloc((size_t)GG*FF*2);
  float*  c1       = (float*) alloc((size_t)GG*4);
  ushort* whhH     = (ushort*)alloc((size_t)GG*HH*2);
  ushort* whhL     = (ushort*)alloc((size_t)GG*HH*2);

  k_zero2<<<(N+255)/256, 256, 0, stream>>>(deg, counters, N);
  k_deg  <<<(E+255)/256, 256, 0, stream>>>(ei, E, deg);
  k_scan <<<1, 1024, 0, stream>>>(deg, offsets, dinv, N);
  k_fill <<<(E+255)/256, 256, 0, stream>>>(ei, E, dinv, offsets, counters, csr2);
  k_prep <<<(GG*HH+255)/256, 256, 0, stream>>>(gcn_w, gcn_b, w_ih, b_ih, w_hh,
                                               m1H, m1L, c1, whhH, whhL);
  k_xt2  <<<(N+15)/16, 256, 0, stream>>>(x, xTh, N);
  k_aggTh<<<(N+3)/4, 256, 0, stream>>>(xTh, offsets, csr2, dinv, aggH, aggL, N);
  k_gru_all<<<(N+31)/32, 256, 0, stream>>>(aggH, aggL, whhH, whhL, m1H, c1, b_hh,
                                           lin_w, lin_b, (float*)d_out, N, P);
}

// Round 9
// 589.078 us; speedup vs baseline: 1.2062x; 1.0519x over previous
//
#include <hip/hip_runtime.h>
#include <hip/hip_bf16.h>
#include <hip/hip_fp16.h>

#define TT 24
#define FF 16
#define HH 64
#define GG 192   // 3*HH

typedef __attribute__((ext_vector_type(4))) float f32x4;
typedef __attribute__((ext_vector_type(8))) _Float16 f16x8;

__device__ __forceinline__ float fast_rcp(float x){ return __builtin_amdgcn_rcpf(x); }
__device__ __forceinline__ float sigmoid_f(float x){
  return fast_rcp(1.0f + __expf(-x));
}
__device__ __forceinline__ float tanh_f(float x){
  float e = __expf(-2.0f * fabsf(x));
  float th = (1.0f - e) * fast_rcp(1.0f + e);
  return copysignf(th, x);
}
__device__ __forceinline__ float4 h4tof4(uint2 u){
  __half2 p0 = *(__half2*)&u.x, p1 = *(__half2*)&u.y;
  float2 f0 = __half22float2(p0), f1 = __half22float2(p1);
  return make_float4(f0.x, f0.y, f1.x, f1.y);
}

// ---------------- CSR build ----------------
__global__ void k_deg(const int* __restrict__ ei, int E, int* __restrict__ deg){
  int i = blockIdx.x*blockDim.x + threadIdx.x;
  if(i<E) atomicAdd(&deg[ei[E+i]], 1);   // dst = ei[E+i]
}

__global__ __launch_bounds__(1024) void k_scan(const int* __restrict__ deg, int* __restrict__ offsets,
                                               float* __restrict__ dinv, int N){
  __shared__ int s[1024];
  int tid = threadIdx.x;
  int CH = (N + 1023) >> 10;
  int lo = tid*CH, hi = min(N, lo+CH);
  int sum=0;
  for(int j=lo;j<hi;j++){
    int d = deg[j];
    dinv[j] = rsqrtf((float)d + 1.0f);
    sum += d;
  }
  s[tid]=sum; __syncthreads();
  for(int o=1;o<1024;o<<=1){
    int v = 0;
    if(tid>=o) v = s[tid-o];
    __syncthreads();
    s[tid] += v;
    __syncthreads();
  }
  int run = s[tid]-sum;
  for(int j=lo;j<hi;j++){ offsets[j]=run; run += deg[j]; }
  if(tid==1023) offsets[N]=s[1023];
}

__global__ void k_fill(const int* __restrict__ ei, int E, const float* __restrict__ dinv,
                       const int* __restrict__ offsets, int* __restrict__ counters,
                       int2* __restrict__ csr2){
  int i = blockIdx.x*blockDim.x + threadIdx.x;
  if(i>=E) return;
  int s = ei[i], d = ei[E+i];
  int slot = offsets[d] + atomicAdd(&counters[d], 1);
  csr2[slot] = make_int2(s, __float_as_int(dinv[s]*dinv[d]));
}

// ---------------- weight prep: M1 = gcn_w @ w_ih^T (f16), c1, w_hh (f16) ----------------
__global__ void k_prep(const float* __restrict__ gcn_w, const float* __restrict__ gcn_b,
                       const float* __restrict__ w_ih, const float* __restrict__ b_ih,
                       const float* __restrict__ w_hh,
                       ushort* __restrict__ m1F, float* __restrict__ c1,
                       ushort* __restrict__ whhF){
  int tid = blockIdx.x*blockDim.x + threadIdx.x;
  if(tid < GG*FF){
    int j = tid >> 4, f = tid & 15;
    float s = 0.f;
    for(int k=0;k<HH;k++) s += gcn_w[f*HH+k]*w_ih[j*HH+k];
    m1F[tid] = __half_as_ushort(__float2half(s));
  } else if (tid < GG*FF + GG){
    int j = tid - GG*FF;
    float s = b_ih[j];
    for(int k=0;k<HH;k++) s += gcn_b[k]*w_ih[j*HH+k];
    c1[j] = s;
  }
  if(tid < GG*HH){
    whhF[tid] = __half_as_ushort(__float2half(w_hh[tid]));
  }
}

// ---------------- transpose+convert: x[t][n][f] fp32 -> xTh[n][t*16+f] fp16 ----------------
__global__ __launch_bounds__(256)
void k_xt2(const float* __restrict__ x, ushort* __restrict__ xTh, int N){
  __shared__ ushort tile[16][392];
  const int nbase = blockIdx.x * 16;
  const int tid = threadIdx.x;
  const int nd = tid >> 4, f = tid & 15;
  const int n = nbase + nd;
  for(int t=0; t<TT; t++){
    float v = (n < N) ? x[((size_t)t*N + n)*FF + f] : 0.f;
    tile[nd][t*16 + f] = __half_as_ushort(__float2half(v));
  }
  __syncthreads();
  uint* xo = (uint*)xTh;
  for(int i = tid; i < 16*192; i += 256){
    int d = i / 192, pos = i - d*192;
    int nn = nbase + d;
    if(nn < N) xo[(size_t)nn*192 + pos] = *(uint*)&tile[d][pos*2];
  }
}

// ---------------- aggregation: wave per dst node, fp16 rows, all 24 t at once ----------------
// output: single fp16 plane aggF[t][n][f]
__global__ __launch_bounds__(256)
void k_aggTh(const ushort* __restrict__ xTh, const int* __restrict__ offsets,
             const int2* __restrict__ csr2, const float* __restrict__ dinv,
             ushort* __restrict__ aggF, int N){
  int wid = (blockIdx.x*blockDim.x + threadIdx.x) >> 6;
  if(wid >= N) return;
  const int l = threadIdx.x & 63;
  const int half = l >> 5, lh = l & 31;
  const int n = wid;

  float4 a0 = make_float4(0.f,0.f,0.f,0.f);
  float4 a1 = make_float4(0.f,0.f,0.f,0.f);
  float4 a2 = make_float4(0.f,0.f,0.f,0.f);

  const int lo = offsets[n], hi = offsets[n+1];
  for(int j = lo; j < hi; j += 4){
    int ja = j + half;
    int jb = j + 2 + half;
    bool okA = ja < hi, okB = jb < hi;
    int2 cA = csr2[okA ? ja : lo];
    int2 cB = csr2[okB ? jb : lo];
    float wA = okA ? __int_as_float(cA.y) : 0.f;
    float wB = okB ? __int_as_float(cB.y) : 0.f;
    const uint2* rA = (const uint2*)(xTh + (size_t)cA.x*384) + lh;
    const uint2* rB = (const uint2*)(xTh + (size_t)cB.x*384) + lh;
    uint2 uA0 = rA[0], uA1 = rA[32], uA2 = rA[64];
    uint2 uB0 = rB[0], uB1 = rB[32], uB2 = rB[64];
    float4 vA0 = h4tof4(uA0), vA1 = h4tof4(uA1), vA2 = h4tof4(uA2);
    float4 vB0 = h4tof4(uB0), vB1 = h4tof4(uB1), vB2 = h4tof4(uB2);
    a0.x += wA*vA0.x; a0.y += wA*vA0.y; a0.z += wA*vA0.z; a0.w += wA*vA0.w;
    a1.x += wA*vA1.x; a1.y += wA*vA1.y; a1.z += wA*vA1.z; a1.w += wA*vA1.w;
    a2.x += wA*vA2.x; a2.y += wA*vA2.y; a2.z += wA*vA2.z; a2.w += wA*vA2.w;
    a0.x += wB*vB0.x; a0.y += wB*vB0.y; a0.z += wB*vB0.z; a0.w += wB*vB0.w;
    a1.x += wB*vB1.x; a1.y += wB*vB1.y; a1.z += wB*vB1.z; a1.w += wB*vB1.w;
    a2.x += wB*vB2.x; a2.y += wB*vB2.y; a2.z += wB*vB2.z; a2.w += wB*vB2.w;
  }
  a0.x += __shfl_xor(a0.x, 32, 64); a0.y += __shfl_xor(a0.y, 32, 64);
  a0.z += __shfl_xor(a0.z, 32, 64); a0.w += __shfl_xor(a0.w, 32, 64);
  a1.x += __shfl_xor(a1.x, 32, 64); a1.y += __shfl_xor(a1.y, 32, 64);
  a1.z += __shfl_xor(a1.z, 32, 64); a1.w += __shfl_xor(a1.w, 32, 64);
  a2.x += __shfl_xor(a2.x, 32, 64); a2.y += __shfl_xor(a2.y, 32, 64);
  a2.z += __shfl_xor(a2.z, 32, 64); a2.w += __shfl_xor(a2.w, 32, 64);

  if(half == 0){
    float sn = dinv[n]; sn *= sn;
    const uint2* rS = (const uint2*)(xTh + (size_t)n*384) + lh;
    float4 s0 = h4tof4(rS[0]), s1 = h4tof4(rS[32]), s2 = h4tof4(rS[64]);
    a0.x += sn*s0.x; a0.y += sn*s0.y; a0.z += sn*s0.z; a0.w += sn*s0.w;
    a1.x += sn*s1.x; a1.y += sn*s1.y; a1.z += sn*s1.z; a1.w += sn*s1.w;
    a2.x += sn*s2.x; a2.y += sn*s2.y; a2.z += sn*s2.z; a2.w += sn*s2.w;
    float4 acc[3] = {a0, a1, a2};
    #pragma unroll
    for(int k=0;k<3;k++){
      int u  = lh + k*32;
      int t  = u >> 2, f4 = u & 3;
      size_t o = ((size_t)t*N + n)*FF + f4*4;
      float4 a = acc[k];
      ushort4 h;
      h.x = __half_as_ushort(__float2half(a.x));
      h.y = __half_as_ushort(__float2half(a.y));
      h.z = __half_as_ushort(__float2half(a.z));
      h.w = __half_as_ushort(__float2half(a.w));
      *(ushort4*)(aggF + o) = h;
    }
  }
}

// ---------------- persistent f16-MFMA GRU, 32 nodes/block ----------------
// block = 256 = 4 waves; wave w owns channels [w*16,w*16+16) for the block's 32 nodes.
// h state: single f16 plane, double-buffered swizzled LDS (8 KB). 9 MFMA per nt.
__global__ __launch_bounds__(256, 4)
void k_gru_all(const ushort* __restrict__ aggF,
               const ushort* __restrict__ whhF, const ushort* __restrict__ m1F,
               const float* __restrict__ c1, const float* __restrict__ bhh,
               const float* __restrict__ lin_w, const float* __restrict__ lin_b,
               float* __restrict__ out, int N, int P){
  __shared__ __align__(16) ushort hb[2][32*64];   // [buf][node*64+ch] swizzled, 8 KB
  const int tid  = threadIdx.x;
  const int l    = tid & 63, w = tid >> 6;
  const int lrow = l & 15;
  const int lgrp = l >> 4;
  const int ch   = w*16 + lrow;
  const int nbase = blockIdx.x * 32;

  // stationary f16 weights
  f16x8 bF[3][2], mS[3];
  #pragma unroll
  for(int g=0; g<3; g++){
    int j = g*HH + w*16 + lrow;
    #pragma unroll
    for(int ks=0; ks<2; ks++)
      bF[g][ks] = *(const f16x8*)(whhF + j*HH + ks*32 + lgrp*8);
    mS[g] = *(const f16x8*)(m1F + j*FF + (lgrp&1)*8);
  }

  const float cbr = c1[ch]      + bhh[ch];
  const float cbz = c1[ch+HH]   + bhh[ch+HH];
  const float c1n = c1[ch+2*HH];
  const float bhn = bhh[ch+2*HH];

  float hreg[8];
  #pragma unroll
  for(int i=0;i<8;i++) hreg[i]=0.f;

  // input A-frags: lgrp<2 carries agg K=0..15; lgrp>=2 is zero
  const bool agAct = (lgrp < 2);
  const size_t ao0 = (size_t)min(nbase      + lrow, N-1)*FF + (lgrp&1)*8;
  const size_t ao1 = (size_t)min(nbase + 16 + lrow, N-1)*FF + (lgrp&1)*8;
  const f16x8 zf = (f16x8){0,0,0,0,0,0,0,0};

  f16x8 cS0 = agAct ? *(const f16x8*)(aggF + ao0) : zf;
  f16x8 cS1 = agAct ? *(const f16x8*)(aggF + ao1) : zf;

  {
    uint* p = (uint*)&hb[0][0];
    for(int i=tid; i<1024; i+=256) p[i]=0u;
  }
  __syncthreads();

  for(int t=0; t<TT; t++){
    const int cur = t & 1, nxt = cur ^ 1;

    // prefetch agg for t+1
    f16x8 pS0 = cS0, pS1 = cS1;
    if(t+1 < TT && agAct){
      const ushort* ap = aggF + (size_t)(t+1)*N*FF;
      pS0 = *(const f16x8*)(ap + ao0);
      pS1 = *(const f16x8*)(ap + ao1);
    }

    #pragma unroll
    for(int nt=0; nt<2; nt++){
      // LDS read of h (single f16 plane)
      f16x8 ahF[2];
      const int r = nt*16 + lrow;
      #pragma unroll
      for(int ks=0; ks<2; ks++){
        int idx = (r*64 + ks*32 + lgrp*8) ^ ((r&7)<<3);
        ahF[ks] = *(const f16x8*)&hb[cur][idx];
      }
      const f16x8 agS = nt ? cS1 : cS0;

      f32x4 aR = {0.f,0.f,0.f,0.f}, aZ = {0.f,0.f,0.f,0.f};
      f32x4 aNi= {0.f,0.f,0.f,0.f}, aNh= {0.f,0.f,0.f,0.f};
      // hidden: h·WH  (K=64, f16)
      aR = __builtin_amdgcn_mfma_f32_16x16x32_f16(ahF[0], bF[0][0], aR, 0,0,0);
      aR = __builtin_amdgcn_mfma_f32_16x16x32_f16(ahF[1], bF[0][1], aR, 0,0,0);
      aZ = __builtin_amdgcn_mfma_f32_16x16x32_f16(ahF[0], bF[1][0], aZ, 0,0,0);
      aZ = __builtin_amdgcn_mfma_f32_16x16x32_f16(ahF[1], bF[1][1], aZ, 0,0,0);
      aNh= __builtin_amdgcn_mfma_f32_16x16x32_f16(ahF[0], bF[2][0], aNh,0,0,0);
      aNh= __builtin_amdgcn_mfma_f32_16x16x32_f16(ahF[1], bF[2][1], aNh,0,0,0);
      // input: agg·M1 (K=16 live in lgrp<2)
      aR  = __builtin_amdgcn_mfma_f32_16x16x32_f16(agS, mS[0], aR, 0,0,0);
      aZ  = __builtin_amdgcn_mfma_f32_16x16x32_f16(agS, mS[1], aZ, 0,0,0);
      aNi = __builtin_amdgcn_mfma_f32_16x16x32_f16(agS, mS[2], aNi,0,0,0);

      #pragma unroll
      for(int i=0;i<4;i++){
        float r_ = sigmoid_f(aR[i] + cbr);
        float z_ = sigmoid_f(aZ[i] + cbz);
        float nn = tanh_f(aNi[i] + c1n + r_*(aNh[i] + bhn));
        int hidx = nt*4 + i;
        float hp = hreg[hidx];
        float hn = nn + z_*(hp - nn);
        hreg[hidx] = hn;
        int noderow = nt*16 + lgrp*4 + i;
        int idx = (noderow*64 + ch) ^ ((noderow&7)<<3);
        hb[nxt][idx] = __half_as_ushort(__float2half(hn));
      }
    }
    __syncthreads();

    cS0 = pS0; cS1 = pS1;
  }

  // ---- fused linear head ----
  float* hs = (float*)&hb[0][0];   // 8 KB = 32 nodes x 64 ch fp32
  #pragma unroll
  for(int hidx=0; hidx<8; hidx++){
    int nt = hidx >> 2, i = hidx & 3;
    int r = nt*16 + lgrp*4 + i;
    hs[r*64 + ch] = hreg[hidx];
  }
  __syncthreads();
  {
    int r = l;
    int node = nbase + r;
    if(r < 32 && node < N){
      float hv[HH];
      #pragma unroll
      for(int q=0;q<16;q++){
        float4 v = *(const float4*)&hs[r*64 + q*4];
        hv[4*q]=v.x; hv[4*q+1]=v.y; hv[4*q+2]=v.z; hv[4*q+3]=v.w;
      }
      for(int p=w; p<P; p+=4){
        float acc = lin_b[p];
        #pragma unroll
        for(int k=0;k<HH;k++) acc += hv[k]*lin_w[p*HH+k];
        out[(size_t)p*N + node] = acc;
      }
    }
  }
}

extern "C" void kernel_launch(void* const* d_in, const int* in_sizes, int n_in,
                              void* d_out, int out_size, void* d_ws, size_t ws_size,
                              hipStream_t stream){
  const float* x     = (const float*)d_in[0];
  const float* gcn_w = (const float*)d_in[2];
  const float* gcn_b = (const float*)d_in[3];
  const float* w_ih  = (const float*)d_in[4];
  const float* w_hh  = (const float*)d_in[5];
  const float* b_ih  = (const float*)d_in[6];
  const float* b_hh  = (const float*)d_in[7];
  const float* lin_w = (const float*)d_in[8];
  const float* lin_b = (const float*)d_in[9];
  const int*   ei    = (const int*)d_in[10];
  const int E = in_sizes[10]/2;
  const int N = in_sizes[0]/(TT*FF);
  const int P = in_sizes[9];

  char* wsp = (char*)d_ws;
  auto alloc = [&](size_t bytes)->void*{ void* p = wsp; wsp += (bytes + 255) & ~(size_t)255; return p; };
  int*    deg      = (int*)   alloc((size_t)N*4);
  int*    counters = (int*)   alloc((size_t)N*4);
  int*    offsets  = (int*)   alloc((size_t)(N+1)*4);
  float*  dinv     = (float*) alloc((size_t)N*4);
  int2*   csr2     = (int2*)  alloc((size_t)E*8);
  ushort* xTh      = (ushort*)alloc((size_t)N*384*2);
  ushort* aggF     = (ushort*)alloc((size_t)TT*N*FF*2);
  ushort* m1F      = (ushort*)alloc((size_t)GG*FF*2);
  float*  c1       = (float*) alloc((size_t)GG*4);
  ushort* whhF     = (ushort*)alloc((size_t)GG*HH*2);

  hipMemsetAsync(deg,      0, (size_t)N*4, stream);
  hipMemsetAsync(counters, 0, (size_t)N*4, stream);

  k_deg  <<<(E+255)/256, 256, 0, stream>>>(ei, E, deg);
  k_scan <<<1, 1024, 0, stream>>>(deg, offsets, dinv, N);
  k_fill <<<(E+255)/256, 256, 0, stream>>>(ei, E, dinv, offsets, counters, csr2);
  k_prep <<<(GG*HH+255)/256, 256, 0, stream>>>(gcn_w, gcn_b, w_ih, b_ih, w_hh,
                                               m1F, c1, whhF);
  k_xt2  <<<(N+15)/16, 256, 0, stream>>>(x, xTh, N);
  k_aggTh<<<(N+3)/4, 256, 0, stream>>>(xTh, offsets, csr2, dinv, aggF, N);
  k_gru_all<<<(N+31)/32, 256, 0, stream>>>(aggF, whhF, m1F, c1, b_hh,
                                           lin_w, lin_b, (float*)d_out, N, P);
}

// Round 10
// 579.180 us; speedup vs baseline: 1.2268x; 1.0171x over previous
//
#include <hip/hip_runtime.h>
#include <hip/hip_bf16.h>
#include <hip/hip_fp16.h>

#define TT 24
#define FF 16
#define HH 64
#define GG 192   // 3*HH

typedef __attribute__((ext_vector_type(4))) float f32x4;
typedef __attribute__((ext_vector_type(8))) _Float16 f16x8;

__device__ __forceinline__ float fast_rcp(float x){ return __builtin_amdgcn_rcpf(x); }
__device__ __forceinline__ float sigmoid_f(float x){
  return fast_rcp(1.0f + __expf(-x));
}
__device__ __forceinline__ float tanh_f(float x){
  float e = __expf(-2.0f * fabsf(x));
  float th = (1.0f - e) * fast_rcp(1.0f + e);
  return copysignf(th, x);
}
__device__ __forceinline__ float4 h4tof4(uint2 u){
  __half2 p0 = *(__half2*)&u.x, p1 = *(__half2*)&u.y;
  float2 f0 = __half22float2(p0), f1 = __half22float2(p1);
  return make_float4(f0.x, f0.y, f1.x, f1.y);
}
__device__ __forceinline__ uint pack_h2(float a, float b){
  ushort ha = __half_as_ushort(__float2half(a));
  ushort hb = __half_as_ushort(__float2half(b));
  return (uint)ha | ((uint)hb << 16);
}

// ---------------- CSR build ----------------
__global__ void k_deg(const int* __restrict__ ei, int E, int* __restrict__ deg){
  int i = blockIdx.x*blockDim.x + threadIdx.x;
  if(i<E) atomicAdd(&deg[ei[E+i]], 1);   // dst = ei[E+i]
}

__global__ __launch_bounds__(1024) void k_scan(const int* __restrict__ deg, int* __restrict__ offsets,
                                               float* __restrict__ dinv, int N){
  __shared__ int s[1024];
  int tid = threadIdx.x;
  int CH = (N + 1023) >> 10;
  int lo = tid*CH, hi = min(N, lo+CH);
  int sum=0;
  for(int j=lo;j<hi;j++){
    int d = deg[j];
    dinv[j] = rsqrtf((float)d + 1.0f);
    sum += d;
  }
  s[tid]=sum; __syncthreads();
  for(int o=1;o<1024;o<<=1){
    int v = 0;
    if(tid>=o) v = s[tid-o];
    __syncthreads();
    s[tid] += v;
    __syncthreads();
  }
  int run = s[tid]-sum;
  for(int j=lo;j<hi;j++){ offsets[j]=run; run += deg[j]; }
  if(tid==1023) offsets[N]=s[1023];
}

__global__ void k_fill(const int* __restrict__ ei, int E, const float* __restrict__ dinv,
                       const int* __restrict__ offsets, int* __restrict__ counters,
                       int2* __restrict__ csr2){
  int i = blockIdx.x*blockDim.x + threadIdx.x;
  if(i>=E) return;
  int s = ei[i], d = ei[E+i];
  int slot = offsets[d] + atomicAdd(&counters[d], 1);
  csr2[slot] = make_int2(s, __float_as_int(dinv[s]*dinv[d]));
}

// ---------------- weight prep: M1 = gcn_w @ w_ih^T (f16), c1, w_hh (f16) ----------------
__global__ void k_prep(const float* __restrict__ gcn_w, const float* __restrict__ gcn_b,
                       const float* __restrict__ w_ih, const float* __restrict__ b_ih,
                       const float* __restrict__ w_hh,
                       ushort* __restrict__ m1F, float* __restrict__ c1,
                       ushort* __restrict__ whhF){
  int tid = blockIdx.x*blockDim.x + threadIdx.x;
  if(tid < GG*FF){
    int j = tid >> 4, f = tid & 15;
    float s = 0.f;
    for(int k=0;k<HH;k++) s += gcn_w[f*HH+k]*w_ih[j*HH+k];
    m1F[tid] = __half_as_ushort(__float2half(s));
  } else if (tid < GG*FF + GG){
    int j = tid - GG*FF;
    float s = b_ih[j];
    for(int k=0;k<HH;k++) s += gcn_b[k]*w_ih[j*HH+k];
    c1[j] = s;
  }
  if(tid < GG*HH){
    whhF[tid] = __half_as_ushort(__float2half(w_hh[tid]));
  }
}

// ---------------- transpose+convert: x[t][n][f] fp32 -> xTh[n][t*16+f] fp16 ----------------
__global__ __launch_bounds__(256)
void k_xt2(const float* __restrict__ x, ushort* __restrict__ xTh, int N){
  __shared__ ushort tile[16][392];
  const int nbase = blockIdx.x * 16;
  const int tid = threadIdx.x;
  const int nd = tid >> 4, f = tid & 15;
  const int n = nbase + nd;
  for(int t=0; t<TT; t++){
    float v = (n < N) ? x[((size_t)t*N + n)*FF + f] : 0.f;
    tile[nd][t*16 + f] = __half_as_ushort(__float2half(v));
  }
  __syncthreads();
  uint* xo = (uint*)xTh;
  for(int i = tid; i < 16*192; i += 256){
    int d = i / 192, pos = i - d*192;
    int nn = nbase + d;
    if(nn < N) xo[(size_t)nn*192 + pos] = *(uint*)&tile[d][pos*2];
  }
}

// ---------------- aggregation: wave per dst node, fp16 rows, all 24 t at once ----------------
__global__ __launch_bounds__(256)
void k_aggTh(const ushort* __restrict__ xTh, const int* __restrict__ offsets,
             const int2* __restrict__ csr2, const float* __restrict__ dinv,
             ushort* __restrict__ aggF, int N){
  int wid = (blockIdx.x*blockDim.x + threadIdx.x) >> 6;
  if(wid >= N) return;
  const int l = threadIdx.x & 63;
  const int half = l >> 5, lh = l & 31;
  const int n = wid;

  float4 a0 = make_float4(0.f,0.f,0.f,0.f);
  float4 a1 = make_float4(0.f,0.f,0.f,0.f);
  float4 a2 = make_float4(0.f,0.f,0.f,0.f);

  const int lo = offsets[n], hi = offsets[n+1];
  for(int j = lo; j < hi; j += 4){
    int ja = j + half;
    int jb = j + 2 + half;
    bool okA = ja < hi, okB = jb < hi;
    int2 cA = csr2[okA ? ja : lo];
    int2 cB = csr2[okB ? jb : lo];
    float wA = okA ? __int_as_float(cA.y) : 0.f;
    float wB = okB ? __int_as_float(cB.y) : 0.f;
    const uint2* rA = (const uint2*)(xTh + (size_t)cA.x*384) + lh;
    const uint2* rB = (const uint2*)(xTh + (size_t)cB.x*384) + lh;
    uint2 uA0 = rA[0], uA1 = rA[32], uA2 = rA[64];
    uint2 uB0 = rB[0], uB1 = rB[32], uB2 = rB[64];
    float4 vA0 = h4tof4(uA0), vA1 = h4tof4(uA1), vA2 = h4tof4(uA2);
    float4 vB0 = h4tof4(uB0), vB1 = h4tof4(uB1), vB2 = h4tof4(uB2);
    a0.x += wA*vA0.x; a0.y += wA*vA0.y; a0.z += wA*vA0.z; a0.w += wA*vA0.w;
    a1.x += wA*vA1.x; a1.y += wA*vA1.y; a1.z += wA*vA1.z; a1.w += wA*vA1.w;
    a2.x += wA*vA2.x; a2.y += wA*vA2.y; a2.z += wA*vA2.z; a2.w += wA*vA2.w;
    a0.x += wB*vB0.x; a0.y += wB*vB0.y; a0.z += wB*vB0.z; a0.w += wB*vB0.w;
    a1.x += wB*vB1.x; a1.y += wB*vB1.y; a1.z += wB*vB1.z; a1.w += wB*vB1.w;
    a2.x += wB*vB2.x; a2.y += wB*vB2.y; a2.z += wB*vB2.z; a2.w += wB*vB2.w;
  }
  a0.x += __shfl_xor(a0.x, 32, 64); a0.y += __shfl_xor(a0.y, 32, 64);
  a0.z += __shfl_xor(a0.z, 32, 64); a0.w += __shfl_xor(a0.w, 32, 64);
  a1.x += __shfl_xor(a1.x, 32, 64); a1.y += __shfl_xor(a1.y, 32, 64);
  a1.z += __shfl_xor(a1.z, 32, 64); a1.w += __shfl_xor(a1.w, 32, 64);
  a2.x += __shfl_xor(a2.x, 32, 64); a2.y += __shfl_xor(a2.y, 32, 64);
  a2.z += __shfl_xor(a2.z, 32, 64); a2.w += __shfl_xor(a2.w, 32, 64);

  if(half == 0){
    float sn = dinv[n]; sn *= sn;
    const uint2* rS = (const uint2*)(xTh + (size_t)n*384) + lh;
    float4 s0 = h4tof4(rS[0]), s1 = h4tof4(rS[32]), s2 = h4tof4(rS[64]);
    a0.x += sn*s0.x; a0.y += sn*s0.y; a0.z += sn*s0.z; a0.w += sn*s0.w;
    a1.x += sn*s1.x; a1.y += sn*s1.y; a1.z += sn*s1.z; a1.w += sn*s1.w;
    a2.x += sn*s2.x; a2.y += sn*s2.y; a2.z += sn*s2.z; a2.w += sn*s2.w;
    float4 acc[3] = {a0, a1, a2};
    #pragma unroll
    for(int k=0;k<3;k++){
      int u  = lh + k*32;
      int t  = u >> 2, f4 = u & 3;
      size_t o = ((size_t)t*N + n)*FF + f4*4;
      float4 a = acc[k];
      ushort4 h;
      h.x = __half_as_ushort(__float2half(a.x));
      h.y = __half_as_ushort(__float2half(a.y));
      h.z = __half_as_ushort(__float2half(a.z));
      h.w = __half_as_ushort(__float2half(a.w));
      *(ushort4*)(aggF + o) = h;
    }
  }
}

// ---------------- barrier-free persistent GRU: 1 wave = 16 nodes x 64 ch ----------------
// Swapped operands: D[ch][node] = mfma(A=W(rows=ch), B=h(cols=node)).
// Per lane: node = l&15 (B/D col), g = l>>4; lane holds D rows g*4+i -> its node's 16 ch.
// h round-trips through a wave-PRIVATE 2KB LDS region (in-order within wave, no barrier).
// Input biases (r,z,ni) folded into the k=16 slot of the input MFMA (agg frag g==2 = 1.0).
__global__ __launch_bounds__(256, 2)
void k_gru_all(const ushort* __restrict__ aggF,
               const ushort* __restrict__ whhF, const ushort* __restrict__ m1F,
               const float* __restrict__ c1, const float* __restrict__ bhh,
               const float* __restrict__ lin_w, const float* __restrict__ lin_b,
               float* __restrict__ out, int N, int P){
  __shared__ __align__(16) uint hw[4][512];   // per-wave 16 nodes x 32 dwords (64 f16)
  const int tid = threadIdx.x;
  const int l = tid & 63, w = tid >> 6;
  const int nd = l & 15, g = l >> 4;
  const int wid = blockIdx.x*4 + w;
  const int node = wid*16 + nd;
  const int nodec = min(node, N-1);
  uint* myh = hw[w];

  // ---- stationary weights (A-frags, rows = ch with ch_in_tile = nd) ----
  f16x8 wAr[4][2], wAz[4][2], wAn[4][2], mAr[4], mAz[4], mAn[4];
  const f16x8 zf = (f16x8){0,0,0,0,0,0,0,0};
  #pragma unroll
  for(int c=0;c<4;c++){
    const int chr =        c*16 + nd;
    const int chz =  HH  + c*16 + nd;
    const int chn = 2*HH + c*16 + nd;
    #pragma unroll
    for(int ks=0;ks<2;ks++){
      wAr[c][ks] = *(const f16x8*)(whhF + chr*HH + ks*32 + g*8);
      wAz[c][ks] = *(const f16x8*)(whhF + chz*HH + ks*32 + g*8);
      wAn[c][ks] = *(const f16x8*)(whhF + chn*HH + ks*32 + g*8);
    }
    mAr[c] = zf; mAz[c] = zf; mAn[c] = zf;
    if(g < 2){
      mAr[c] = *(const f16x8*)(m1F + chr*FF + g*8);
      mAz[c] = *(const f16x8*)(m1F + chz*FF + g*8);
      mAn[c] = *(const f16x8*)(m1F + chn*FF + g*8);
    } else if(g == 2){
      mAr[c][0] = (_Float16)(c1[chr] + bhh[chr]);
      mAz[c][0] = (_Float16)(c1[chz] + bhh[chz]);
      mAn[c][0] = (_Float16)(c1[chn]);
    }
  }

  // bhn (hidden n-gate bias) per lane's 16 ch
  float4 bb[4];
  #pragma unroll
  for(int c=0;c<4;c++) bb[c] = *(const float4*)(bhh + 2*HH + c*16 + g*4);

  float hreg[16];
  #pragma unroll
  for(int i=0;i<16;i++) hreg[i]=0.f;

  // zero wave-private h (no barrier needed: same wave)
  for(int i=l;i<512;i+=64) myh[i]=0u;

  // agg B-frag: g<2 -> agg[node][g*8..]; g==2 -> k=16 slot = 1.0 (bias); g==3 -> 0
  f16x8 acst = zf;
  if(g==2) acst[0] = (_Float16)1.0f;
  f16x8 cAg = acst;
  if(g < 2) cAg = *(const f16x8*)(aggF + (size_t)nodec*FF + g*8);

  const int swz = (nd & 7) << 2;

  for(int t=0; t<TT; t++){
    // h B-frags from wave-private LDS (swizzled)
    f16x8 hB0, hB1;
    {
      int a0 = nd*32 + ((0*16 + g*4) ^ swz);
      int a1 = nd*32 + ((1*16 + g*4) ^ swz);
      hB0 = *(const f16x8*)(myh + a0);
      hB1 = *(const f16x8*)(myh + a1);
    }

    // prefetch agg for t+1
    f16x8 pAg = cAg;
    if(g < 2 && t+1 < TT)
      pAg = *(const f16x8*)(aggF + (size_t)(t+1)*N*FF + (size_t)nodec*FF + g*8);

    #pragma unroll
    for(int c=0;c<4;c++){
      f32x4 R  = {0.f,0.f,0.f,0.f};
      f32x4 Z  = {0.f,0.f,0.f,0.f};
      f32x4 Nh = {0.f,0.f,0.f,0.f};
      f32x4 Ni = {0.f,0.f,0.f,0.f};
      R  = __builtin_amdgcn_mfma_f32_16x16x32_f16(wAr[c][0], hB0, R , 0,0,0);
      R  = __builtin_amdgcn_mfma_f32_16x16x32_f16(wAr[c][1], hB1, R , 0,0,0);
      R  = __builtin_amdgcn_mfma_f32_16x16x32_f16(mAr[c],    cAg, R , 0,0,0);
      Z  = __builtin_amdgcn_mfma_f32_16x16x32_f16(wAz[c][0], hB0, Z , 0,0,0);
      Z  = __builtin_amdgcn_mfma_f32_16x16x32_f16(wAz[c][1], hB1, Z , 0,0,0);
      Z  = __builtin_amdgcn_mfma_f32_16x16x32_f16(mAz[c],    cAg, Z , 0,0,0);
      Nh = __builtin_amdgcn_mfma_f32_16x16x32_f16(wAn[c][0], hB0, Nh, 0,0,0);
      Nh = __builtin_amdgcn_mfma_f32_16x16x32_f16(wAn[c][1], hB1, Nh, 0,0,0);
      Ni = __builtin_amdgcn_mfma_f32_16x16x32_f16(mAn[c],    cAg, Ni, 0,0,0);

      const float bbv[4] = {bb[c].x, bb[c].y, bb[c].z, bb[c].w};
      #pragma unroll
      for(int i=0;i<4;i++){
        float r_ = sigmoid_f(R[i]);
        float z_ = sigmoid_f(Z[i]);
        float nn = tanh_f(Ni[i] + r_*(Nh[i] + bbv[i]));
        float hp = hreg[c*4+i];
        float hv = nn + z_*(hp - nn);
        hreg[c*4+i] = hv;
      }
      uint p0 = pack_h2(hreg[c*4+0], hreg[c*4+1]);
      uint p1 = pack_h2(hreg[c*4+2], hreg[c*4+3]);
      int dwb = c*8 + g*2;
      myh[nd*32 + ((dwb+0) ^ swz)] = p0;
      myh[nd*32 + ((dwb+1) ^ swz)] = p1;
    }
    cAg = pAg;
  }

  // ---- fused linear head: per-lane partial dot over its 16 ch, reduce over g ----
  for(int p=0; p<P; p++){
    float acc = 0.f;
    #pragma unroll
    for(int c=0;c<4;c++){
      float4 lw4 = *(const float4*)(lin_w + p*HH + c*16 + g*4);
      acc += lw4.x*hreg[c*4+0] + lw4.y*hreg[c*4+1]
           + lw4.z*hreg[c*4+2] + lw4.w*hreg[c*4+3];
    }
    acc += __shfl_xor(acc, 16, 64);
    acc += __shfl_xor(acc, 32, 64);
    if(g == 0 && node < N) out[(size_t)p*N + node] = acc + lin_b[p];
  }
}

extern "C" void kernel_launch(void* const* d_in, const int* in_sizes, int n_in,
                              void* d_out, int out_size, void* d_ws, size_t ws_size,
                              hipStream_t stream){
  const float* x     = (const float*)d_in[0];
  const float* gcn_w = (const float*)d_in[2];
  const float* gcn_b = (const float*)d_in[3];
  const float* w_ih  = (const float*)d_in[4];
  const float* w_hh  = (const float*)d_in[5];
  const float* b_ih  = (const float*)d_in[6];
  const float* b_hh  = (const float*)d_in[7];
  const float* lin_w = (const float*)d_in[8];
  const float* lin_b = (const float*)d_in[9];
  const int*   ei    = (const int*)d_in[10];
  const int E = in_sizes[10]/2;
  const int N = in_sizes[0]/(TT*FF);
  const int P = in_sizes[9];

  char* wsp = (char*)d_ws;
  auto alloc = [&](size_t bytes)->void*{ void* p = wsp; wsp += (bytes + 255) & ~(size_t)255; return p; };
  int*    deg      = (int*)   alloc((size_t)N*4);
  int*    counters = (int*)   alloc((size_t)N*4);
  int*    offsets  = (int*)   alloc((size_t)(N+1)*4);
  float*  dinv     = (float*) alloc((size_t)N*4);
  int2*   csr2     = (int2*)  alloc((size_t)E*8);
  ushort* xTh      = (ushort*)alloc((size_t)N*384*2);
  ushort* aggF     = (ushort*)alloc((size_t)TT*N*FF*2);
  ushort* m1F      = (ushort*)alloc((size_t)GG*FF*2);
  float*  c1       = (float*) alloc((size_t)GG*4);
  ushort* whhF     = (ushort*)alloc((size_t)GG*HH*2);

  hipMemsetAsync(deg,      0, (size_t)N*4, stream);
  hipMemsetAsync(counters, 0, (size_t)N*4, stream);

  k_deg  <<<(E+255)/256, 256, 0, stream>>>(ei, E, deg);
  k_scan <<<1, 1024, 0, stream>>>(deg, offsets, dinv, N);
  k_fill <<<(E+255)/256, 256, 0, stream>>>(ei, E, dinv, offsets, counters, csr2);
  k_prep <<<(GG*HH+255)/256, 256, 0, stream>>>(gcn_w, gcn_b, w_ih, b_ih, w_hh,
                                               m1F, c1, whhF);
  k_xt2  <<<(N+15)/16, 256, 0, stream>>>(x, xTh, N);
  k_aggTh<<<(N+3)/4, 256, 0, stream>>>(xTh, offsets, csr2, dinv, aggF, N);
  k_gru_all<<<(N+63)/64, 256, 0, stream>>>(aggF, whhF, m1F, c1, b_hh,
                                           lin_w, lin_b, (float*)d_out, N, P);
}